// Round 1
// baseline (954.366 us; speedup 1.0000x reference)
//
#include <hip/hip_runtime.h>
#include <cstdint>
#include <cstddef>

#define MR 2048
#define NC 4096
#define M3 683
#define SEG 16
#define HSEG 128      // MR/SEG
#define H3 43         // ceil(M3/SEG)
#define RAD 49
#define NORM (1.0f/9604.0f)

__device__ __forceinline__ float sp(float v){
  // jax.nn.softplus = max(x,0) + log1p(exp(-|x|))
  return fmaxf(v, 0.0f) + log1pf(expf(-fabsf(v)));
}

// ---- segmented column scans (two-pass) ----

__global__ void seg_sum_decay(const float* __restrict__ bneg, const float* __restrict__ dcol,
                              float* __restrict__ Pd){
  int s = blockIdx.x;
  int j = blockIdx.y*blockDim.x + threadIdx.x;
  int i0 = s*H3, i1 = min(M3, i0+H3);
  float acc = 0.f;
  for(int i=i0;i<i1;i++) acc += bneg[i*NC+j]*sp(dcol[i*NC+j]);
  Pd[s*NC+j] = acc;
}

__global__ void seg_sum_b(const float* __restrict__ b, const float* __restrict__ w,
                          float* __restrict__ Pb){
  int s = blockIdx.x;
  int j = blockIdx.y*blockDim.x + threadIdx.x;
  int i0 = s*HSEG;
  float acc=0.f;
  for(int i=i0;i<i0+HSEG;i++) acc += b[i*NC+j]*sp(w[i*NC+j]);
  Pb[s*NC+j]=acc;
}

__global__ void scan_excl(float* __restrict__ P, int segs){
  int j = blockIdx.x*blockDim.x + threadIdx.x;
  float run=0.f;
  for(int s=0;s<segs;s++){
    float t = P[s*NC+j];
    P[s*NC+j] = run;
    run += t;
  }
}

__global__ void decay_finalize(const float* __restrict__ bneg, const float* __restrict__ dcol,
                               const float* __restrict__ Pd, float* __restrict__ dc){
  int s=blockIdx.x;
  int j=blockIdx.y*blockDim.x+threadIdx.x;
  int i0=s*H3, i1=min(M3,i0+H3);
  float run = Pd[s*NC+j];
  for(int i=i0;i<i1;i++){
    run += bneg[i*NC+j]*sp(dcol[i*NC+j]);
    dc[i*NC+j]=run;
  }
}

// ---- phase 1: b cumsum + decay upsample + b_adpt + x ----
__global__ void phase1(const float* __restrict__ b, const float* __restrict__ w,
                       const float* __restrict__ Pb, const float* __restrict__ dc,
                       const float* __restrict__ fg, const float* __restrict__ fm,
                       const float* __restrict__ bold, const float* __restrict__ hX,
                       const float* __restrict__ recon,
                       float* __restrict__ out0, float* __restrict__ out3,
                       float* __restrict__ X){
  int s=blockIdx.x;
  int j=blockIdx.y*blockDim.x+threadIdx.x;
  int i0=s*HSEG;
  float run = Pb[s*NC+j];
  for(int rr=0;rr<HSEG;rr++){
    int i=i0+rr;
    run += b[i*NC+j]*sp(w[i*NC+j]);
    // jax.image.resize 'linear', half-pixel centers, edge weights renormalize == clamp
    float c = (i+0.5f)*(683.0f/2048.0f)-0.5f;
    float fl = floorf(c);
    float f = c-fl;
    int a0=(int)fl, a1=a0+1;
    a0 = a0<0?0:(a0>M3-1?M3-1:a0);
    a1 = a1<0?0:(a1>M3-1?M3-1:a1);
    float d = (1.f-f)*dc[a0*NC+j] + f*dc[a1*NC+j];
    float bf = run + d*(1.f - fg[i*NC+j]);
    out3[i*NC+j]=bf;
    float fmv = fm[i*NC+j];
    float ba = bf*fmv + bold[i*NC+j]*(1.f-fmv);
    out0[i*NC+j]=ba;
    X[i*NC+j] = hX[(4*i)*NC+j] + ba - recon[i*NC+j];
  }
}

// ---- horizontal 98-window sums via in-LDS row prefix (replicate-pad aware) ----
// window for output j covers cols j-48 .. j+49, clamped with multiplicity

__global__ __launch_bounds__(256) void hbox_sq(const float* __restrict__ X,
                         float* __restrict__ H1, float* __restrict__ H2){
  __shared__ float C1[NC+1];
  __shared__ float C2[NC+1];
  __shared__ float ts1[256];
  __shared__ float ts2[256];
  int row=blockIdx.x, tid=threadIdx.x;
  const float* xr = X + (size_t)row*NC;
  float v1[16], v2[16];
  int base=tid*16;
  float run1=0.f,run2=0.f;
  const float4* p4 = reinterpret_cast<const float4*>(xr+base);
  #pragma unroll
  for(int q=0;q<4;q++){
    float4 fq=p4[q];
    float e[4]={fq.x,fq.y,fq.z,fq.w};
    #pragma unroll
    for(int t=0;t<4;t++){
      run1+=e[t];      v1[q*4+t]=run1;
      run2+=e[t]*e[t]; v2[q*4+t]=run2;
    }
  }
  ts1[tid]=run1; ts2[tid]=run2;
  __syncthreads();
  for(int off=1; off<256; off<<=1){
    float a1 = (tid>=off)? ts1[tid-off]:0.f;
    float a2 = (tid>=off)? ts2[tid-off]:0.f;
    __syncthreads();
    ts1[tid]+=a1; ts2[tid]+=a2;
    __syncthreads();
  }
  float ex1 = ts1[tid]-run1, ex2 = ts2[tid]-run2;
  if(tid==0){C1[0]=0.f;C2[0]=0.f;}
  #pragma unroll
  for(int e=0;e<16;e++){ C1[base+1+e]=ex1+v1[e]; C2[base+1+e]=ex2+v2[e]; }
  __syncthreads();
  float first1=C1[1],       last1=C1[NC]-C1[NC-1];
  float first2=C2[1],       last2=C2[NC]-C2[NC-1];
  float* h1 = H1+(size_t)row*NC;
  float* h2 = H2+(size_t)row*NC;
  #pragma unroll
  for(int k=0;k<16;k++){
    int j=k*256+tid;
    int lo=j-48, hi=j+49;
    int li = lo<0?0:lo;
    int hc = hi>NC-1?NC-1:hi;
    float s1=C1[hc+1]-C1[li];
    float s2=C2[hc+1]-C2[li];
    if(lo<0){ s1+=(float)(-lo)*first1; s2+=(float)(-lo)*first2; }
    if(hi>NC-1){ s1+=(float)(hi-(NC-1))*last1; s2+=(float)(hi-(NC-1))*last2; }
    h1[j]=s1; h2[j]=s2;
  }
}

__global__ __launch_bounds__(256) void hbox_two(const float* __restrict__ A,
                         const float* __restrict__ B,
                         float* __restrict__ H1, float* __restrict__ H2){
  __shared__ float C1[NC+1];
  __shared__ float C2[NC+1];
  __shared__ float ts1[256];
  __shared__ float ts2[256];
  int row=blockIdx.x, tid=threadIdx.x;
  const float* ar = A + (size_t)row*NC;
  const float* br = B + (size_t)row*NC;
  float v1[16], v2[16];
  int base=tid*16;
  float run1=0.f,run2=0.f;
  const float4* pa = reinterpret_cast<const float4*>(ar+base);
  const float4* pb = reinterpret_cast<const float4*>(br+base);
  #pragma unroll
  for(int q=0;q<4;q++){
    float4 fa=pa[q]; float4 fb=pb[q];
    float ea[4]={fa.x,fa.y,fa.z,fa.w};
    float eb[4]={fb.x,fb.y,fb.z,fb.w};
    #pragma unroll
    for(int t=0;t<4;t++){
      run1+=ea[t]; v1[q*4+t]=run1;
      run2+=eb[t]; v2[q*4+t]=run2;
    }
  }
  ts1[tid]=run1; ts2[tid]=run2;
  __syncthreads();
  for(int off=1; off<256; off<<=1){
    float a1 = (tid>=off)? ts1[tid-off]:0.f;
    float a2 = (tid>=off)? ts2[tid-off]:0.f;
    __syncthreads();
    ts1[tid]+=a1; ts2[tid]+=a2;
    __syncthreads();
  }
  float ex1 = ts1[tid]-run1, ex2 = ts2[tid]-run2;
  if(tid==0){C1[0]=0.f;C2[0]=0.f;}
  #pragma unroll
  for(int e=0;e<16;e++){ C1[base+1+e]=ex1+v1[e]; C2[base+1+e]=ex2+v2[e]; }
  __syncthreads();
  float first1=C1[1], last1=C1[NC]-C1[NC-1];
  float first2=C2[1], last2=C2[NC]-C2[NC-1];
  float* h1 = H1+(size_t)row*NC;
  float* h2 = H2+(size_t)row*NC;
  #pragma unroll
  for(int k=0;k<16;k++){
    int j=k*256+tid;
    int lo=j-48, hi=j+49;
    int li = lo<0?0:lo;
    int hc = hi>NC-1?NC-1:hi;
    float s1=C1[hc+1]-C1[li];
    float s2=C2[hc+1]-C2[li];
    if(lo<0){ s1+=(float)(-lo)*first1; s2+=(float)(-lo)*first2; }
    if(hi>NC-1){ s1+=(float)(hi-(NC-1))*last1; s2+=(float)(hi-(NC-1))*last2; }
    h1[j]=s1; h2[j]=s2;
  }
}

// ---- vertical 98-window sliding sums (rows i-48..i+49 clamped) ----

__global__ void vbox_stage1(const float* __restrict__ H1, const float* __restrict__ H2,
                            float* __restrict__ Aimg, float* __restrict__ BBimg){
  int tile = blockIdx.x;
  int j = blockIdx.y*blockDim.x + threadIdx.x;
  int i0 = tile*HSEG;
  float Sa=0.f, Sb=0.f;
  for(int c=i0-48;c<=i0+49;c++){
    int cc = c<0?0:(c>MR-1?MR-1:c);
    Sa += H1[cc*NC+j]; Sb += H2[cc*NC+j];
  }
  for(int rr=0;rr<HSEG;rr++){
    int i=i0+rr;
    if(rr>0){
      int up = i+49; up = up>MR-1?MR-1:up;
      int dn = i-49; dn = dn<0?0:dn;
      Sa += H1[up*NC+j]-H1[dn*NC+j];
      Sb += H2[up*NC+j]-H2[dn*NC+j];
    }
    float mx = Sa*NORM, mx2 = Sb*NORM;
    float var = mx2 - mx*mx;
    float A = var/(var+1.0f);
    float bb = mx - A*mx;
    Aimg[i*NC+j]=A; BBimg[i*NC+j]=bb;
  }
}

__global__ void vbox_stage2(const float* __restrict__ H1, const float* __restrict__ H2,
                            const float* __restrict__ X, float* __restrict__ diff){
  int tile = blockIdx.x;
  int j = blockIdx.y*blockDim.x + threadIdx.x;
  int i0 = tile*HSEG;
  float Sa=0.f, Sb=0.f;
  for(int c=i0-48;c<=i0+49;c++){
    int cc = c<0?0:(c>MR-1?MR-1:c);
    Sa += H1[cc*NC+j]; Sb += H2[cc*NC+j];
  }
  for(int rr=0;rr<HSEG;rr++){
    int i=i0+rr;
    if(rr>0){
      int up = i+49; up = up>MR-1?MR-1:up;
      int dn = i-49; dn = dn<0?0:dn;
      Sa += H1[up*NC+j]-H1[dn*NC+j];
      Sb += H2[up*NC+j]-H2[dn*NC+j];
    }
    diff[i*NC+j] = (Sa*NORM)*X[i*NC+j] + Sb*NORM;
  }
}

// ---- phase 3: row-diff, clip, scale, column cumsum, final subtract ----

__global__ void phase3_segsum(const float* __restrict__ diff, const float* __restrict__ ww,
                              float* __restrict__ Pc){
  int s=blockIdx.x;
  int j=blockIdx.y*blockDim.x+threadIdx.x;
  int i0=s*HSEG;
  float dpre = (i0==0)? diff[j] : diff[(i0-1)*NC+j];
  float acc=0.f;
  for(int rr=0;rr<HSEG;rr++){
    int i=i0+rr;
    float dcur=diff[i*NC+j];
    float v=dcur-dpre; v = v>0.f? v:0.f;
    acc += v*sp(ww[i*NC+j]);
    dpre=dcur;
  }
  Pc[s*NC+j]=acc;
}

__global__ void phase3_final(const float* __restrict__ diff, const float* __restrict__ ww,
                             const float* __restrict__ Pc,
                             float* __restrict__ out0, float* __restrict__ out2){
  int s=blockIdx.x;
  int j=blockIdx.y*blockDim.x+threadIdx.x;
  int i0=s*HSEG;
  float dpre = (i0==0)? diff[j] : diff[(i0-1)*NC+j];
  float run = Pc[s*NC+j];
  for(int rr=0;rr<HSEG;rr++){
    int i=i0+rr;
    float dcur=diff[i*NC+j];
    float v=dcur-dpre; v = v>0.f? v:0.f;
    run += v*sp(ww[i*NC+j]);
    dpre=dcur;
    out2[i*NC+j]=run;
    out0[i*NC+j]=out0[i*NC+j]-run;
  }
}

extern "C" void kernel_launch(void* const* d_in, const int* in_sizes, int n_in,
                              void* d_out, int out_size, void* d_ws, size_t ws_size,
                              hipStream_t stream){
  const float* b    = (const float*)d_in[0];
  const float* bneg = (const float*)d_in[1];
  const float* fg   = (const float*)d_in[2];
  const float* hX   = (const float*)d_in[3];
  const float* recon= (const float*)d_in[4];
  const float* fm   = (const float*)d_in[5];
  const float* bold = (const float*)d_in[6];
  // d_in[7] = r (int scalar, ==4) — shapes hardcoded
  const float* w    = (const float*)d_in[8];
  const float* dcol = (const float*)d_in[9];
  const float* ww   = (const float*)d_in[10];

  float* out  = (float*)d_out;
  float* out0 = out;                       // b_adpt (holds b_adpt0 until phase3_final)
  float* out1 = out + (size_t)MR*NC;       // diff   (holds A_img as scratch mid-pipe)
  float* out2 = out + 2ull*MR*NC;          // diff_adpt (holds bb_img as scratch mid-pipe)
  float* out3 = out + 3ull*MR*NC;          // b

  float* wsf = (float*)d_ws;
  float* X  = wsf;                         // 2048*4096
  float* H1 = wsf + 1ull*MR*NC;            // 2048*4096
  float* H2 = wsf + 2ull*MR*NC;            // 2048*4096
  float* DC = wsf + 3ull*MR*NC;            // 683*4096
  float* Pb = DC + (size_t)M3*NC;          // 16*4096
  float* Pd = Pb + (size_t)SEG*NC;         // 16*4096
  float* Pc = Pd + (size_t)SEG*NC;         // 16*4096

  dim3 segGrid(SEG, NC/256);

  seg_sum_decay<<<segGrid,256,0,stream>>>(bneg,dcol,Pd);
  seg_sum_b    <<<segGrid,256,0,stream>>>(b,w,Pb);
  scan_excl    <<<NC/256,256,0,stream>>>(Pd,SEG);
  scan_excl    <<<NC/256,256,0,stream>>>(Pb,SEG);
  decay_finalize<<<segGrid,256,0,stream>>>(bneg,dcol,Pd,DC);
  phase1       <<<segGrid,256,0,stream>>>(b,w,Pb,DC,fg,fm,bold,hX,recon,out0,out3,X);
  hbox_sq      <<<MR,256,0,stream>>>(X,H1,H2);
  vbox_stage1  <<<dim3(SEG,NC/256),256,0,stream>>>(H1,H2,out1,out2);
  hbox_two     <<<MR,256,0,stream>>>(out1,out2,H1,H2);
  vbox_stage2  <<<dim3(SEG,NC/256),256,0,stream>>>(H1,H2,X,out1);
  phase3_segsum<<<segGrid,256,0,stream>>>(out1,ww,Pc);
  scan_excl    <<<NC/256,256,0,stream>>>(Pc,SEG);
  phase3_final <<<segGrid,256,0,stream>>>(out1,ww,Pc,out0,out2);
}

// Round 3
// 695.177 us; speedup vs baseline: 1.3728x; 1.3728x over previous
//
#include <hip/hip_runtime.h>
#include <cstdint>
#include <cstddef>

#define MR 2048
#define NC 4096
#define M3 683
#define SEG 64        // segments for 2048-row cumsums
#define HSEG 32       // MR/SEG
#define SEGD 22       // segments for 683-row cumsum
#define H3D 32        // rows per decay segment (ceil(683/22)=32)
#define VT 64         // vertical box tile height
#define VTILES 32     // MR/VT
#define NORM (1.0f/9604.0f)

__device__ __forceinline__ float sp(float v){
  // jax.nn.softplus = max(x,0) + log1p(exp(-|x|))
  return fmaxf(v, 0.0f) + log1pf(expf(-fabsf(v)));
}

// ---- segmented column scans (two-pass), caching the elementwise product ----

__global__ void seg_sum_decay(const float* __restrict__ bneg, const float* __restrict__ dcol,
                              float* __restrict__ TD, float* __restrict__ Pd){
  int s = blockIdx.x;
  int j = blockIdx.y*blockDim.x + threadIdx.x;
  int i0 = s*H3D, i1 = min(M3, i0+H3D);
  float acc = 0.f;
  for(int i=i0;i<i1;i++){
    float t = bneg[i*NC+j]*sp(dcol[i*NC+j]);
    TD[i*NC+j]=t;
    acc += t;
  }
  Pd[s*NC+j] = acc;
}

__global__ void seg_sum_b(const float* __restrict__ b, const float* __restrict__ w,
                          float* __restrict__ TB, float* __restrict__ Pb){
  int s = blockIdx.x;
  int j = blockIdx.y*blockDim.x + threadIdx.x;
  int i0 = s*HSEG;
  float acc=0.f;
  #pragma unroll 4
  for(int i=i0;i<i0+HSEG;i++){
    float t = b[i*NC+j]*sp(w[i*NC+j]);
    TB[i*NC+j]=t;
    acc += t;
  }
  Pb[s*NC+j]=acc;
}

__global__ void scan_excl(float* __restrict__ P, int segs){
  int j = blockIdx.x*blockDim.x + threadIdx.x;
  float run=0.f;
  for(int s=0;s<segs;s++){
    float t = P[s*NC+j];
    P[s*NC+j] = run;
    run += t;
  }
}

__global__ void decay_finalize(const float* __restrict__ TD,
                               const float* __restrict__ Pd, float* __restrict__ dc){
  int s=blockIdx.x;
  int j=blockIdx.y*blockDim.x+threadIdx.x;
  int i0=s*H3D, i1=min(M3,i0+H3D);
  float run = Pd[s*NC+j];
  for(int i=i0;i<i1;i++){
    run += TD[i*NC+j];
    dc[i*NC+j]=run;
  }
}

// ---- phase 1: b cumsum + decay upsample + b_adpt + x ----
__global__ void phase1(const float* __restrict__ TB,
                       const float* __restrict__ Pb, const float* __restrict__ dc,
                       const float* __restrict__ fg, const float* __restrict__ fm,
                       const float* __restrict__ bold, const float* __restrict__ hX,
                       const float* __restrict__ recon,
                       float* __restrict__ out0, float* __restrict__ out3,
                       float* __restrict__ X){
  int s=blockIdx.x;
  int j=blockIdx.y*blockDim.x+threadIdx.x;
  int i0=s*HSEG;
  float run = Pb[s*NC+j];
  #pragma unroll 4
  for(int rr=0;rr<HSEG;rr++){
    int i=i0+rr;
    run += TB[i*NC+j];
    // jax.image.resize 'linear', half-pixel centers, edge weights renormalize == clamp
    float c = (i+0.5f)*(683.0f/2048.0f)-0.5f;
    float fl = floorf(c);
    float f = c-fl;
    int a0=(int)fl, a1=a0+1;
    a0 = a0<0?0:(a0>M3-1?M3-1:a0);
    a1 = a1<0?0:(a1>M3-1?M3-1:a1);
    float d = (1.f-f)*dc[a0*NC+j] + f*dc[a1*NC+j];
    float bf = run + d*(1.f - fg[i*NC+j]);
    out3[i*NC+j]=bf;
    float fmv = fm[i*NC+j];
    float ba = bf*fmv + bold[i*NC+j]*(1.f-fmv);
    out0[i*NC+j]=ba;
    X[i*NC+j] = hX[(4*i)*NC+j] + ba - recon[i*NC+j];
  }
}

// ---- horizontal 98-window sums via in-LDS row prefix (replicate-pad aware) ----

__global__ __launch_bounds__(256) void hbox_sq(const float* __restrict__ X,
                         float* __restrict__ H1, float* __restrict__ H2){
  __shared__ float C1[NC+1];
  __shared__ float C2[NC+1];
  __shared__ float ts1[256];
  __shared__ float ts2[256];
  int row=blockIdx.x, tid=threadIdx.x;
  const float* xr = X + (size_t)row*NC;
  float v1[16], v2[16];
  int base=tid*16;
  float run1=0.f,run2=0.f;
  const float4* p4 = reinterpret_cast<const float4*>(xr+base);
  #pragma unroll
  for(int q=0;q<4;q++){
    float4 fq=p4[q];
    float e[4]={fq.x,fq.y,fq.z,fq.w};
    #pragma unroll
    for(int t=0;t<4;t++){
      run1+=e[t];      v1[q*4+t]=run1;
      run2+=e[t]*e[t]; v2[q*4+t]=run2;
    }
  }
  ts1[tid]=run1; ts2[tid]=run2;
  __syncthreads();
  for(int off=1; off<256; off<<=1){
    float a1 = (tid>=off)? ts1[tid-off]:0.f;
    float a2 = (tid>=off)? ts2[tid-off]:0.f;
    __syncthreads();
    ts1[tid]+=a1; ts2[tid]+=a2;
    __syncthreads();
  }
  float ex1 = ts1[tid]-run1, ex2 = ts2[tid]-run2;
  if(tid==0){C1[0]=0.f;C2[0]=0.f;}
  #pragma unroll
  for(int e=0;e<16;e++){ C1[base+1+e]=ex1+v1[e]; C2[base+1+e]=ex2+v2[e]; }
  __syncthreads();
  float first1=C1[1],       last1=C1[NC]-C1[NC-1];
  float first2=C2[1],       last2=C2[NC]-C2[NC-1];
  float* h1 = H1+(size_t)row*NC;
  float* h2 = H2+(size_t)row*NC;
  #pragma unroll
  for(int k=0;k<16;k++){
    int j=k*256+tid;
    int lo=j-48, hi=j+49;
    int li = lo<0?0:lo;
    int hc = hi>NC-1?NC-1:hi;
    float s1=C1[hc+1]-C1[li];
    float s2=C2[hc+1]-C2[li];
    if(lo<0){ s1+=(float)(-lo)*first1; s2+=(float)(-lo)*first2; }
    if(hi>NC-1){ s1+=(float)(hi-(NC-1))*last1; s2+=(float)(hi-(NC-1))*last2; }
    h1[j]=s1; h2[j]=s2;
  }
}

__global__ __launch_bounds__(256) void hbox_two(const float* __restrict__ A,
                         const float* __restrict__ B,
                         float* __restrict__ H1, float* __restrict__ H2){
  __shared__ float C1[NC+1];
  __shared__ float C2[NC+1];
  __shared__ float ts1[256];
  __shared__ float ts2[256];
  int row=blockIdx.x, tid=threadIdx.x;
  const float* ar = A + (size_t)row*NC;
  const float* br = B + (size_t)row*NC;
  float v1[16], v2[16];
  int base=tid*16;
  float run1=0.f,run2=0.f;
  const float4* pa = reinterpret_cast<const float4*>(ar+base);
  const float4* pb = reinterpret_cast<const float4*>(br+base);
  #pragma unroll
  for(int q=0;q<4;q++){
    float4 fa=pa[q]; float4 fb=pb[q];
    float ea[4]={fa.x,fa.y,fa.z,fa.w};
    float eb[4]={fb.x,fb.y,fb.z,fb.w};
    #pragma unroll
    for(int t=0;t<4;t++){
      run1+=ea[t]; v1[q*4+t]=run1;
      run2+=eb[t]; v2[q*4+t]=run2;
    }
  }
  ts1[tid]=run1; ts2[tid]=run2;
  __syncthreads();
  for(int off=1; off<256; off<<=1){
    float a1 = (tid>=off)? ts1[tid-off]:0.f;
    float a2 = (tid>=off)? ts2[tid-off]:0.f;
    __syncthreads();
    ts1[tid]+=a1; ts2[tid]+=a2;
    __syncthreads();
  }
  float ex1 = ts1[tid]-run1, ex2 = ts2[tid]-run2;
  if(tid==0){C1[0]=0.f;C2[0]=0.f;}
  #pragma unroll
  for(int e=0;e<16;e++){ C1[base+1+e]=ex1+v1[e]; C2[base+1+e]=ex2+v2[e]; }
  __syncthreads();
  float first1=C1[1], last1=C1[NC]-C1[NC-1];
  float first2=C2[1], last2=C2[NC]-C2[NC-1];
  float* h1 = H1+(size_t)row*NC;
  float* h2 = H2+(size_t)row*NC;
  #pragma unroll
  for(int k=0;k<16;k++){
    int j=k*256+tid;
    int lo=j-48, hi=j+49;
    int li = lo<0?0:lo;
    int hc = hi>NC-1?NC-1:hi;
    float s1=C1[hc+1]-C1[li];
    float s2=C2[hc+1]-C2[li];
    if(lo<0){ s1+=(float)(-lo)*first1; s2+=(float)(-lo)*first2; }
    if(hi>NC-1){ s1+=(float)(hi-(NC-1))*last1; s2+=(float)(hi-(NC-1))*last2; }
    h1[j]=s1; h2[j]=s2;
  }
}

// ---- vertical 98-window sliding sums (rows i-48..i+49 clamped) ----

__global__ void vbox_stage1(const float* __restrict__ H1, const float* __restrict__ H2,
                            float* __restrict__ Aimg, float* __restrict__ BBimg){
  int tile = blockIdx.x;
  int j = blockIdx.y*blockDim.x + threadIdx.x;
  int i0 = tile*VT;
  float Sa=0.f, Sb=0.f;
  for(int c=i0-48;c<=i0+49;c++){
    int cc = c<0?0:(c>MR-1?MR-1:c);
    Sa += H1[cc*NC+j]; Sb += H2[cc*NC+j];
  }
  #pragma unroll 4
  for(int rr=0;rr<VT;rr++){
    int i=i0+rr;
    if(rr>0){
      int up = i+49; up = up>MR-1?MR-1:up;
      int dn = i-49; dn = dn<0?0:dn;
      Sa += H1[up*NC+j]-H1[dn*NC+j];
      Sb += H2[up*NC+j]-H2[dn*NC+j];
    }
    float mx = Sa*NORM, mx2 = Sb*NORM;
    float var = mx2 - mx*mx;
    float A = var/(var+1.0f);
    float bb = mx - A*mx;
    Aimg[i*NC+j]=A; BBimg[i*NC+j]=bb;
  }
}

// ---- vbox stage2 fused with phase3's diff/clip/scale partial-sum ----
// S (the per-row clipped/scaled increments) lands in out2 (diff_adpt slot),
// whose previous content (bb_img) is dead after hbox_two. NO aliasing with
// H1/H2/X which are still read here.

__global__ void vbox2_fused(const float* __restrict__ H1, const float* __restrict__ H2,
                            const float* __restrict__ X, const float* __restrict__ ww,
                            float* __restrict__ diff, float* __restrict__ S,
                            float* __restrict__ Pc){
  int tile = blockIdx.x;
  int j = blockIdx.y*blockDim.x + threadIdx.x;
  int i0 = tile*VT;
  int istart = (tile==0)? 0 : i0-1;
  float Sa=0.f, Sb=0.f;
  for(int c=istart-48;c<=istart+49;c++){
    int cc = c<0?0:(c>MR-1?MR-1:c);
    Sa += H1[cc*NC+j]; Sb += H2[cc*NC+j];
  }
  float dpre, acc=0.f;
  if(tile==0){
    float d0 = (Sa*NORM)*X[j] + Sb*NORM;
    diff[j]=d0; S[j]=0.f; dpre=d0;
    for(int i=1;i<VT;i++){
      int up = i+49; up = up>MR-1?MR-1:up;
      int dn = i-49; dn = dn<0?0:dn;
      Sa += H1[up*NC+j]-H1[dn*NC+j];
      Sb += H2[up*NC+j]-H2[dn*NC+j];
      float d = (Sa*NORM)*X[i*NC+j] + Sb*NORM;
      diff[i*NC+j]=d;
      float v = d-dpre; v = v>0.f? v:0.f;
      float sv = v*sp(ww[i*NC+j]);
      S[i*NC+j]=sv; acc+=sv; dpre=d;
    }
  } else {
    dpre = (Sa*NORM)*X[(size_t)istart*NC+j] + Sb*NORM;
    for(int rr=0;rr<VT;rr++){
      int i=i0+rr;
      int up = i+49; up = up>MR-1?MR-1:up;
      int dn = i-49; dn = dn<0?0:dn;
      Sa += H1[up*NC+j]-H1[dn*NC+j];
      Sb += H2[up*NC+j]-H2[dn*NC+j];
      float d = (Sa*NORM)*X[i*NC+j] + Sb*NORM;
      diff[i*NC+j]=d;
      float v = d-dpre; v = v>0.f? v:0.f;
      float sv = v*sp(ww[i*NC+j]);
      S[i*NC+j]=sv; acc+=sv; dpre=d;
    }
  }
  Pc[tile*NC+j]=acc;
}

// ---- phase 3 final: column cumsum of S (in out2, overwritten in place),
//      write diff_adpt, update b_adpt ----

__global__ void phase3_final(const float* __restrict__ Pc,
                             float* __restrict__ out0, float* __restrict__ out2){
  int s=blockIdx.x;
  int j=blockIdx.y*blockDim.x+threadIdx.x;
  int i0=s*VT;
  float run = Pc[s*NC+j];
  #pragma unroll 4
  for(int rr=0;rr<VT;rr++){
    int i=i0+rr;
    run += out2[i*NC+j];         // S value written by vbox2_fused
    out2[i*NC+j]=run;            // overwrite in place with cumsum
    out0[i*NC+j]=out0[i*NC+j]-run;
  }
}

extern "C" void kernel_launch(void* const* d_in, const int* in_sizes, int n_in,
                              void* d_out, int out_size, void* d_ws, size_t ws_size,
                              hipStream_t stream){
  const float* b    = (const float*)d_in[0];
  const float* bneg = (const float*)d_in[1];
  const float* fg   = (const float*)d_in[2];
  const float* hX   = (const float*)d_in[3];
  const float* recon= (const float*)d_in[4];
  const float* fm   = (const float*)d_in[5];
  const float* bold = (const float*)d_in[6];
  // d_in[7] = r (int scalar, ==4) — shapes hardcoded
  const float* w    = (const float*)d_in[8];
  const float* dcol = (const float*)d_in[9];
  const float* ww   = (const float*)d_in[10];

  float* out  = (float*)d_out;
  float* out0 = out;                       // b_adpt
  float* out1 = out + (size_t)MR*NC;       // diff (A_img scratch mid-pipe)
  float* out2 = out + 2ull*MR*NC;          // diff_adpt (bb_img scratch, then S, then cumsum)
  float* out3 = out + 3ull*MR*NC;          // b

  float* wsf = (float*)d_ws;
  float* X  = wsf;                         // MR*NC
  float* H1 = wsf + 1ull*MR*NC;            // MR*NC   (TD early)
  float* H2 = wsf + 2ull*MR*NC;            // MR*NC   (TB early)
  float* DC = wsf + 3ull*MR*NC;            // M3*NC
  float* Pb = DC + (size_t)M3*NC;          // SEG*NC
  float* Pd = Pb + (size_t)SEG*NC;         // SEGD*NC
  float* Pc = Pd + (size_t)SEGD*NC;        // VTILES*NC
  float* TD = H1;                          // M3*NC  (dead before hbox_sq writes H1)
  float* TB = H2;                          // MR*NC  (dead before hbox_sq writes H2)

  seg_sum_decay<<<dim3(SEGD,NC/256),256,0,stream>>>(bneg,dcol,TD,Pd);
  seg_sum_b    <<<dim3(SEG, NC/256),256,0,stream>>>(b,w,TB,Pb);
  scan_excl    <<<NC/256,256,0,stream>>>(Pd,SEGD);
  scan_excl    <<<NC/256,256,0,stream>>>(Pb,SEG);
  decay_finalize<<<dim3(SEGD,NC/256),256,0,stream>>>(TD,Pd,DC);
  phase1       <<<dim3(SEG, NC/256),256,0,stream>>>(TB,Pb,DC,fg,fm,bold,hX,recon,out0,out3,X);
  hbox_sq      <<<MR,256,0,stream>>>(X,H1,H2);
  vbox_stage1  <<<dim3(VTILES,NC/256),256,0,stream>>>(H1,H2,out1,out2);
  hbox_two     <<<MR,256,0,stream>>>(out1,out2,H1,H2);
  vbox2_fused  <<<dim3(VTILES,NC/256),256,0,stream>>>(H1,H2,X,ww,out1,out2,Pc);
  scan_excl    <<<NC/256,256,0,stream>>>(Pc,VTILES);
  phase3_final <<<dim3(VTILES,NC/256),256,0,stream>>>(Pc,out0,out2);
}